// Round 1
// baseline (103.000 us; speedup 1.0000x reference)
//
#include <hip/hip_runtime.h>

#define STEPS 32
#define H 256
#define W 256
#define ROWS_PER_BLOCK 64
#define NCHUNKS (H / ROWS_PER_BLOCK)   // 4
#define NIMG (64 * 3)                  // 192

// One block per (image, 64-row chunk). Thread = column. Per-thread private LDS
// histogram hist[k*256 + tid]: bank = tid%32 fixed per lane -> 2-way aliasing
// per wave64 = free; atomicAdd on a private slot emits no-return ds_add_u32
// (no RAW latency chain, no contention).
__global__ __launch_bounds__(256) void ecc_kernel(const float* __restrict__ x,
                                                  float* __restrict__ out) {
    __shared__ int hist[STEPS * 256];  // 32 KB
    const int tid   = threadIdx.x;
    const int chunk = blockIdx.x & (NCHUNKS - 1);
    const int bc    = blockIdx.x >> 2;             // 0..191
    const float* img = x + (size_t)bc * (H * W);

    // Zero private slots (no sync needed before use: strictly per-thread).
    int* myhist = hist + tid;
#pragma unroll
    for (int k = 0; k < STEPS; ++k) myhist[k * 256] = 0;

    const int r0 = chunk * ROWS_PER_BLOCK;
    const int j = tid;
    const bool has_right = (j < W - 1);

    float a = img[r0 * W + j];
    float b = has_right ? img[r0 * W + j + 1] : 0.0f;

    for (int i = r0; i < r0 + ROWS_PER_BLOCK; ++i) {
        const bool has_down = (i < H - 1);
        float c = 0.0f, d = 0.0f;
        if (has_down) {
            c = img[(i + 1) * W + j];
            if (has_right) d = img[(i + 1) * W + j + 1];
        }
        // vertex (+1): always
        {
            int k = (int)ceilf(a * 31.0f);
            k = k < 31 ? k : 31;                 // overflow safety (f<1 so moot)
            atomicAdd(&myhist[k * 256], 1);
        }
        // horizontal edge (-1): j < W-1
        if (has_right) {
            float he = fmaxf(a, b);
            int k = (int)ceilf(he * 31.0f);
            k = k < 31 ? k : 31;
            atomicAdd(&myhist[k * 256], -1);
        }
        if (has_down) {
            // vertical edge (-1)
            float ve = fmaxf(a, c);
            int k = (int)ceilf(ve * 31.0f);
            k = k < 31 ? k : 31;
            atomicAdd(&myhist[k * 256], -1);
            // square (+1)
            if (has_right) {
                float sq = fmaxf(fmaxf(a, b), fmaxf(c, d));
                int ks = (int)ceilf(sq * 31.0f);
                ks = ks < 31 ? ks : 31;
                atomicAdd(&myhist[ks * 256], 1);
            }
        }
        a = c;
        b = d;
    }
    __syncthreads();

    // Tree-reduce across the thread dimension: hist[k][0] = sum over 256 threads.
    // Lanes tid access bank tid%32 -> conflict-free (2-way aliasing).
#pragma unroll
    for (int s = 128; s >= 1; s >>= 1) {
        if (tid < s) {
#pragma unroll
            for (int k = 0; k < STEPS; ++k)
                hist[k * 256 + tid] += hist[k * 256 + tid + s];
        }
        __syncthreads();
    }

    // Cumsum (linear, so partial cumsums add) + global atomic merge of chunks.
    if (tid < STEPS) {
        int sum = 0;
        for (int k = 0; k <= tid; ++k) sum += hist[k * 256];  // same-addr broadcast reads
        atomicAdd(&out[bc * STEPS + tid], (float)sum);
    }
}

extern "C" void kernel_launch(void* const* d_in, const int* in_sizes, int n_in,
                              void* d_out, int out_size, void* d_ws, size_t ws_size,
                              hipStream_t stream) {
    const float* x = (const float*)d_in[0];
    float* out = (float*)d_out;
    // d_out is re-poisoned to 0xAA before every launch; we accumulate atomically.
    hipMemsetAsync(out, 0, (size_t)out_size * sizeof(float), stream);
    ecc_kernel<<<NIMG * NCHUNKS, 256, 0, stream>>>(x, out);
}

// Round 2
// 89.137 us; speedup vs baseline: 1.1555x; 1.1555x over previous
//
#include <hip/hip_runtime.h>

#define STEPS 32
#define H 256
#define W 256
#define R 8                // rows per wave band
#define NIMG 192
#define BLOCKS_PER_IMG 8   // 4 waves/block * 8 rows/wave = 32 rows/block

// bin(f) = ceil(f*31), clipped. Monotone, so bin(max(a,b)) = max(bin a, bin b):
// all edge/square bins are integer maxes of vertex bins.
__device__ __forceinline__ int binf(float f) {
    int k = (int)ceilf(f * 31.0f);
    return k > 31 ? 31 : k;
}

// Per-thread private byte-packed histograms: word (k>>2), byte field (k&3).
// Separate pos/neg arrays so every update is +1 (no cross-field borrow).
// Address = (k>>2)*256 + tid -> bank = tid%32, fixed per lane: wave64 has
// 2-way aliasing only = free. atomicAdd on a private slot -> no-return
// ds_add_u32, fire-and-forget (no RAW chain).
__global__ __launch_bounds__(256) void ecc_kernel(const float* __restrict__ x,
                                                  float* __restrict__ out) {
    __shared__ int hpos[8 * 256];   // 8 KB
    __shared__ int hneg[8 * 256];   // 8 KB
    __shared__ int cnt[STEPS];
    const int tid  = threadIdx.x;
    const int lane = tid & 63;
    const int wave = tid >> 6;
    const int bc   = blockIdx.x >> 3;          // image*channel 0..191
    const int bg   = blockIdx.x & 7;           // band group within image
    const int r0   = (bg * 4 + wave) * R;      // first owned row of this wave
    const float* img = x + (size_t)bc * (H * W);

#pragma unroll
    for (int w = 0; w < 8; ++w) { hpos[(w << 8) + tid] = 0; hneg[(w << 8) + tid] = 0; }
    // no sync needed: slots are strictly per-thread until the first barrier

    const bool has_right = (lane < 63);        // lane 63 owns cols 252..255; col 255 = W-1

#define ADDP(k) atomicAdd(&hpos[(((k) >> 2) << 8) + tid], 1 << (((k) & 3) << 3))
#define ADDN(k) atomicAdd(&hneg[(((k) >> 2) << 8) + tid], 1 << (((k) & 3) << 3))

    // lane owns cols 4*lane .. 4*lane+3; one coalesced float4 per row
    float4 cur = *((const float4*)(img + (size_t)r0 * W) + lane);
    int c0 = binf(cur.x), c1 = binf(cur.y), c2 = binf(cur.z), c3 = binf(cur.w);
    int cR = __shfl_down(c0, 1);               // right neighbor's first col bin
    int h0 = max(c0, c1), h1 = max(c1, c2), h2 = max(c2, c3), h3 = max(c3, cR);

    for (int i = r0; i < r0 + R; ++i) {
        const bool down = (i + 1 < H);         // wave-uniform
        float4 nx;
        if (down) nx = *((const float4*)(img + (size_t)(i + 1) * W) + lane);
        // vertices (+)
        ADDP(c0); ADDP(c1); ADDP(c2); ADDP(c3);
        // horizontal edges (-)
        ADDN(h0); ADDN(h1); ADDN(h2);
        if (has_right) ADDN(h3);
        if (down) {
            int n0 = binf(nx.x), n1 = binf(nx.y), n2 = binf(nx.z), n3 = binf(nx.w);
            int nR = __shfl_down(n0, 1);       // uniform branch: all lanes execute
            int g0 = max(n0, n1), g1 = max(n1, n2), g2 = max(n2, n3), g3 = max(n3, nR);
            // vertical edges (-)
            int v0 = max(c0, n0), v1 = max(c1, n1), v2 = max(c2, n2), v3 = max(c3, n3);
            ADDN(v0); ADDN(v1); ADDN(v2); ADDN(v3);
            // squares (+): max of the two horizontal-edge bins
            ADDP(max(h0, g0)); ADDP(max(h1, g1)); ADDP(max(h2, g2));
            if (has_right) ADDP(max(h3, g3));
            c0 = n0; c1 = n1; c2 = n2; c3 = n3;
            h0 = g0; h1 = g1; h2 = g2; h3 = g3;
        }
    }
    __syncthreads();

    // one packed fold 256->128: per-thread field max 64, sum <=128 < 255, safe
    if (tid < 128) {
#pragma unroll
        for (int w = 0; w < 8; ++w) {
            hpos[(w << 8) + tid] += hpos[(w << 8) + tid + 128];
            hneg[(w << 8) + tid] += hneg[(w << 8) + tid + 128];
        }
    }
    __syncthreads();

    // 32 threads extract their bin's byte across 128 columns
    if (tid < STEPS) {
        const int base = (tid >> 2) << 8;
        const int sh = (tid & 3) << 3;
        int s = 0;
        for (int t = 0; t < 128; ++t) {
            s += (hpos[base + t] >> sh) & 0xff;
            s -= (hneg[base + t] >> sh) & 0xff;
        }
        cnt[tid] = s;
    }
    __syncthreads();

    // cumsum (linear => per-block partial cumsums add) + global merge
    if (tid < STEPS) {
        int s = 0;
        for (int k = 0; k <= tid; ++k) s += cnt[k];   // broadcast reads
        atomicAdd(&out[bc * STEPS + tid], (float)s);
    }
#undef ADDP
#undef ADDN
}

extern "C" void kernel_launch(void* const* d_in, const int* in_sizes, int n_in,
                              void* d_out, int out_size, void* d_ws, size_t ws_size,
                              hipStream_t stream) {
    const float* x = (const float*)d_in[0];
    float* out = (float*)d_out;
    // d_out is re-poisoned before every launch; we accumulate atomically into it.
    hipMemsetAsync(out, 0, (size_t)out_size * sizeof(float), stream);
    ecc_kernel<<<NIMG * BLOCKS_PER_IMG, 256, 0, stream>>>(x, out);
}

// Round 3
// 84.139 us; speedup vs baseline: 1.2242x; 1.0594x over previous
//
#include <hip/hip_runtime.h>

#define STEPS 32
#define H 256
#define W 256
#define R 8                // rows per wave band
#define NIMG 192
#define BLOCKS_PER_IMG 8   // 4 waves/block * 8 rows/wave = 32 rows/block

// bin(f) = ceil(f*31). Input is uniform [0,1): f*31 <= 31.0 after rounding,
// so k in [0,31] and no clip is needed (absmax was exactly 0 in R1/R2 with
// this binning; monotone, so bin(max(a,b)) = max(bin a, bin b)).
__device__ __forceinline__ int binf(float f) {
    return (int)ceilf(f * 31.0f);
}

// 64 shared histogram copies, unpacked int: hist[k*64 + (tid&63)].
// Intra-wave lane->column is 1:1 (bank = lane%32, 2-way aliasing = free);
// cross-wave same-slot collisions are legal (ds_add) and rare.
// Per update: 1 v_lshl_add addr + 1 no-return ds_add_u32 with preloaded +/-1.
__global__ __launch_bounds__(256) void ecc_kernel(const float* __restrict__ x,
                                                  float* __restrict__ out) {
    __shared__ int hist[STEPS * 64];   // 8 KB
    const int tid  = threadIdx.x;
    const int lane = tid & 63;
    const int wave = tid >> 6;
    const int col  = lane;             // histogram copy index
    const int bc   = blockIdx.x >> 3;  // image*channel 0..191
    const int bg   = blockIdx.x & 7;   // band group within image
    const int r0   = (bg * 4 + wave) * R;
    const float* img = x + (size_t)bc * (H * W);

#pragma unroll
    for (int w = 0; w < 8; ++w) hist[(w << 8) + tid] = 0;
    __syncthreads();                   // copies are shared across waves now

    const bool has_right = (lane < 63);  // lane 63's col 255 has no right edge

#define ADD(k, v) atomicAdd(&hist[((k) << 6) + col], (v))

    // lane owns cols 4*lane .. 4*lane+3; one coalesced float4 per row
    float4 cur = *((const float4*)(img + (size_t)r0 * W) + lane);
    int c0 = binf(cur.x), c1 = binf(cur.y), c2 = binf(cur.z), c3 = binf(cur.w);
    int cR = __shfl_down(c0, 1);
    int h0 = max(c0, c1), h1 = max(c1, c2), h2 = max(c2, c3), h3 = max(c3, cR);

    for (int i = r0; i < r0 + R; ++i) {
        const bool down = (i + 1 < H);   // wave-uniform
        float4 nx;
        if (down) nx = *((const float4*)(img + (size_t)(i + 1) * W) + lane);
        // vertices (+1)
        ADD(c0, 1); ADD(c1, 1); ADD(c2, 1); ADD(c3, 1);
        // horizontal edges (-1)
        ADD(h0, -1); ADD(h1, -1); ADD(h2, -1);
        if (has_right) ADD(h3, -1);
        if (down) {
            int n0 = binf(nx.x), n1 = binf(nx.y), n2 = binf(nx.z), n3 = binf(nx.w);
            int nR = __shfl_down(n0, 1);  // uniform branch: all lanes execute
            int g0 = max(n0, n1), g1 = max(n1, n2), g2 = max(n2, n3), g3 = max(n3, nR);
            // vertical edges (-1)
            ADD(max(c0, n0), -1); ADD(max(c1, n1), -1);
            ADD(max(c2, n2), -1); ADD(max(c3, n3), -1);
            // squares (+1): max of the two horizontal-edge bins
            ADD(max(h0, g0), 1); ADD(max(h1, g1), 1); ADD(max(h2, g2), 1);
            if (has_right) ADD(max(h3, g3), 1);
            c0 = n0; c1 = n1; c2 = n2; c3 = n3;
            h0 = g0; h1 = g1; h2 = g2; h3 = g3;
        }
    }
#undef ADD
    __syncthreads();

    // 32 threads: sum own bin over 64 columns, rotated so banks are distinct
    // across the half-wave ((t+tid)%32 distinct for tid=0..31), then a 5-step
    // shfl_up inclusive scan gives the cumsum; merge chunks via global atomic.
    if (tid < STEPS) {
        int s = 0;
#pragma unroll 8
        for (int t = 0; t < 64; ++t)
            s += hist[(tid << 6) + ((t + tid) & 63)];
#pragma unroll
        for (int d = 1; d < STEPS; d <<= 1) {
            int u = __shfl_up(s, d);
            if (tid >= d) s += u;
        }
        atomicAdd(&out[bc * STEPS + tid], (float)s);
    }
}

extern "C" void kernel_launch(void* const* d_in, const int* in_sizes, int n_in,
                              void* d_out, int out_size, void* d_ws, size_t ws_size,
                              hipStream_t stream) {
    const float* x = (const float*)d_in[0];
    float* out = (float*)d_out;
    // d_out is re-poisoned before every launch; we accumulate atomically into it.
    hipMemsetAsync(out, 0, (size_t)out_size * sizeof(float), stream);
    ecc_kernel<<<NIMG * BLOCKS_PER_IMG, 256, 0, stream>>>(x, out);
}

// Round 4
// 84.050 us; speedup vs baseline: 1.2255x; 1.0011x over previous
//
#include <hip/hip_runtime.h>

#define STEPS 32
#define H 256
#define W 256
#define R 8                // rows per wave band
#define NIMG 192
#define BLOCKS_PER_IMG 8   // 4 waves/block * 8 rows/wave = 32 rows/block

// bin(f) = ceil(f*31). Input uniform [0,1): k in [0,31], no clip needed
// (absmax exactly 0 in R1-R3). Monotone => bin(max(a,b)) = max(bin a, bin b).
__device__ __forceinline__ int binf(float f) {
    return (int)ceilf(f * 31.0f);
}

// 64 shared histogram copies: hist[k*64 + lane]. Bank = lane%32 (2-way
// aliasing per wave64 = free). ds_add no-return atomics, cross-wave
// collisions legal and rare. The row loop is software-pipelined 5 deep:
// >=4 float4 loads in flight per wave at all times (the R3 version issued
// one dependent load per iteration and stalled ~80% on HBM latency).
__global__ __launch_bounds__(256) void ecc_kernel(const float* __restrict__ x,
                                                  float* __restrict__ out) {
    __shared__ int hist[STEPS * 64];   // 8 KB
    const int tid  = threadIdx.x;
    const int lane = tid & 63;
    const int wave = tid >> 6;
    const int bc   = blockIdx.x >> 3;  // image*channel 0..191
    const int bg   = blockIdx.x & 7;   // band group within image
    const int r0   = (bg * 4 + wave) * R;
    // lane owns cols 4*lane..4*lane+3; row r = rowp[r*64]
    const float4* rowp = (const float4*)(x + (size_t)bc * (H * W)) + lane;

#pragma unroll
    for (int w = 0; w < 8; ++w) hist[(w << 8) + tid] = 0;
    __syncthreads();

    const bool has_right = (lane < 63);     // col 255 has no right edge
    const bool last_band = (r0 + R == H);   // band containing row 255

#define ADD(k, v) atomicAdd(&hist[((k) << 6) + lane], (v))

    // prime the 5-slot register queue with rows r0..r0+4 (r0+4 <= 252, valid)
    float4 q[5];
#pragma unroll
    for (int t = 0; t < 5; ++t) q[t] = rowp[(size_t)(r0 + t) * (W / 4)];

    // current-row bins + horizontal-edge maxes from q[0]
    int c0 = binf(q[0].x), c1 = binf(q[0].y), c2 = binf(q[0].z), c3 = binf(q[0].w);
    int cR = __shfl_down(c0, 1);
    int h0 = max(c0, c1), h1 = max(c1, c2), h2 = max(c2, c3), h3 = max(c3, cR);

#pragma unroll
    for (int t = 0; t < R; ++t) {
        const bool down = (t < R - 1) || !last_band;   // wave-uniform
        // next row (r0+t+1) sits in slot (t+1)%5; convert first so the slot's
        // producer load is the oldest outstanding vmcnt
        float4 nq = q[(t + 1) % 5];
        int n0 = binf(nq.x), n1 = binf(nq.y), n2 = binf(nq.z), n3 = binf(nq.w);
        int nR = __shfl_down(n0, 1);
        int g0 = max(n0, n1), g1 = max(n1, n2), g2 = max(n2, n3), g3 = max(n3, nR);
        // prefetch row r0+t+5 into the just-freed slot t%5 (cur was consumed)
        if (t <= 3 && (t < 3 || !last_band))
            q[t % 5] = rowp[(size_t)(r0 + t + 5) * (W / 4)];
        // vertices (+1)
        ADD(c0, 1); ADD(c1, 1); ADD(c2, 1); ADD(c3, 1);
        // horizontal edges (-1)
        ADD(h0, -1); ADD(h1, -1); ADD(h2, -1);
        if (has_right) ADD(h3, -1);
        if (down) {
            // vertical edges (-1)
            ADD(max(c0, n0), -1); ADD(max(c1, n1), -1);
            ADD(max(c2, n2), -1); ADD(max(c3, n3), -1);
            // squares (+1): max of the two horizontal-edge bins
            ADD(max(h0, g0), 1); ADD(max(h1, g1), 1); ADD(max(h2, g2), 1);
            if (has_right) ADD(max(h3, g3), 1);
        }
        c0 = n0; c1 = n1; c2 = n2; c3 = n3;
        h0 = g0; h1 = g1; h2 = g2; h3 = g3;
    }
#undef ADD
    __syncthreads();

    // 32 threads: sum own bin over 64 columns (rotated => distinct banks),
    // 5-step shfl_up inclusive scan = cumsum, global atomic merges bands.
    if (tid < STEPS) {
        int s = 0;
#pragma unroll 8
        for (int t = 0; t < 64; ++t)
            s += hist[(tid << 6) + ((t + tid) & 63)];
#pragma unroll
        for (int d = 1; d < STEPS; d <<= 1) {
            int u = __shfl_up(s, d);
            if (tid >= d) s += u;
        }
        atomicAdd(&out[bc * STEPS + tid], (float)s);
    }
}

extern "C" void kernel_launch(void* const* d_in, const int* in_sizes, int n_in,
                              void* d_out, int out_size, void* d_ws, size_t ws_size,
                              hipStream_t stream) {
    const float* x = (const float*)d_in[0];
    float* out = (float*)d_out;
    // d_out is re-poisoned before every launch; we accumulate atomically into it.
    hipMemsetAsync(out, 0, (size_t)out_size * sizeof(float), stream);
    ecc_kernel<<<NIMG * BLOCKS_PER_IMG, 256, 0, stream>>>(x, out);
}